// Round 2
// baseline (4733.635 us; speedup 1.0000x reference)
//
#include <hip/hip_runtime.h>
#include <math.h>

#define SEQ 1024
#define DIM 1024
#define FDIM 4096
#define NBATCH 8
#define NHEAD 16
#define DHEAD 64
#define NROWS (NBATCH * SEQ)   // 8192

// ======================= mask canonicalization =======================
// key_padding_mask is bool in the reference; the harness may hand it to us as
// 1-byte bools or 4-byte ints. Decide by content: if any of the first 1024
// 32-bit words exceeds 1, it must be byte layout (4 packed bools per word).
__global__ __launch_bounds__(256)
void canon_mask_k(const void* __restrict__ raw, int* __restrict__ outm, int n)
{
    const unsigned int*  w  = (const unsigned int*)raw;
    const unsigned char* cb = (const unsigned char*)raw;
    __shared__ int flag;
    if (threadIdx.x == 0) flag = 0;
    __syncthreads();
    int bad = 0;
    for (int i = threadIdx.x; i < 1024; i += 256)
        if (w[i] > 1u) bad = 1;
    if (bad) flag = 1;          // benign race: everyone writes 1
    __syncthreads();
    const bool is_i32 = (flag == 0);
    const int idx = blockIdx.x * 256 + threadIdx.x;
    if (idx < n) outm[idx] = is_i32 ? (w[idx] != 0u) : (cb[idx] != 0);
}

// ======================= LayerNorm (+optional residual add) =======================
__device__ __forceinline__ void block_reduce2(float& s, float& ss)
{
    #pragma unroll
    for (int off = 32; off > 0; off >>= 1) {
        s  += __shfl_down(s,  off, 64);
        ss += __shfl_down(ss, off, 64);
    }
    __shared__ float sh[8];
    const int wid  = threadIdx.x >> 6;
    const int lane = threadIdx.x & 63;
    if (lane == 0) { sh[wid] = s; sh[4 + wid] = ss; }
    __syncthreads();
    s  = sh[0] + sh[1] + sh[2] + sh[3];
    ss = sh[4] + sh[5] + sh[6] + sh[7];
}

// out = LN(in)*g+b (+ res). One block per row. NV float4 per thread (cols = NV*1024).
template<int NV>
__global__ __launch_bounds__(256)
void ln_k(const float* __restrict__ in, const float* __restrict__ gw,
          const float* __restrict__ bw, const float* __restrict__ res,
          float* __restrict__ out)
{
    constexpr int COLS = NV * 1024;
    const size_t base = (size_t)blockIdx.x * COLS;
    const int t = threadIdx.x;
    float4 v[NV];
    float s = 0.f, ss = 0.f;
    #pragma unroll
    for (int i = 0; i < NV; ++i) {
        v[i] = *(const float4*)(in + base + (i * 256 + t) * 4);
        s  += v[i].x + v[i].y + v[i].z + v[i].w;
        ss += v[i].x * v[i].x + v[i].y * v[i].y + v[i].z * v[i].z + v[i].w * v[i].w;
    }
    block_reduce2(s, ss);
    const float mean = s * (1.f / COLS);
    const float var  = ss * (1.f / COLS) - mean * mean;
    const float rstd = rsqrtf(var + 1e-3f);
    #pragma unroll
    for (int i = 0; i < NV; ++i) {
        const int col = (i * 256 + t) * 4;
        const float4 g4 = *(const float4*)(gw + col);
        const float4 b4 = *(const float4*)(bw + col);
        float4 o;
        o.x = (v[i].x - mean) * rstd * g4.x + b4.x;
        o.y = (v[i].y - mean) * rstd * g4.y + b4.y;
        o.z = (v[i].z - mean) * rstd * g4.z + b4.z;
        o.w = (v[i].w - mean) * rstd * g4.w + b4.w;
        if (res) {
            const float4 r4 = *(const float4*)(res + base + col);
            o.x += r4.x; o.y += r4.y; o.z += r4.z; o.w += r4.w;
        }
        *(float4*)(out + base + col) = o;
    }
}

// ======================= tiled fp32 GEMM with fused epilogues =======================
// C[M,N] = A[M,K] @ W[K,N] (+ epilogue). BM=128, BN=64, BK=16, 256 thr, 8x4 micro.
#define EPI_NONE  0
#define EPI_VMASK 1
#define EPI_GELU  2
#define EPI_FC2   3

__device__ __forceinline__ float gelu_exact(float x)
{
    return 0.5f * x * (1.f + erff(x * 0.70710678118654752440f));
}

template<int EPI>
__global__ __launch_bounds__(256)
void gemm_k(const float* __restrict__ A, const float* __restrict__ W,
            const float* __restrict__ bias, float* __restrict__ out,
            int M, int K, int N,
            const int* __restrict__ mask, const float* __restrict__ resid,
            const float* __restrict__ lam)
{
    __shared__ float As[16][128];
    __shared__ float Bs[16][64];
    const int t    = threadIdx.x;
    const int row0 = blockIdx.y * 128;
    const int n0   = blockIdx.x * 64;
    const int tx = t & 15, ty = t >> 4;
    // staging indices
    const int am = t >> 2;            // 0..63
    const int ak = (t & 3) * 4;       // 0,4,8,12
    const int bk = t >> 4;            // 0..15
    const int bn = (t & 15) * 4;      // 0..60

    float acc[8][4] = {};
    for (int k0 = 0; k0 < K; k0 += 16) {
        #pragma unroll
        for (int hh = 0; hh < 2; ++hh) {
            const int m = am + hh * 64;
            const float4 av = *(const float4*)(A + (size_t)(row0 + m) * K + k0 + ak);
            As[ak + 0][m] = av.x; As[ak + 1][m] = av.y;
            As[ak + 2][m] = av.z; As[ak + 3][m] = av.w;
        }
        *(float4*)(&Bs[bk][bn]) = *(const float4*)(W + (size_t)(k0 + bk) * N + n0 + bn);
        __syncthreads();
        #pragma unroll
        for (int kk = 0; kk < 16; ++kk) {
            const float4 a0 = *(const float4*)(&As[kk][ty * 8]);
            const float4 a1 = *(const float4*)(&As[kk][ty * 8 + 4]);
            const float4 b4 = *(const float4*)(&Bs[kk][tx * 4]);
            const float ar[8] = {a0.x, a0.y, a0.z, a0.w, a1.x, a1.y, a1.z, a1.w};
            const float br[4] = {b4.x, b4.y, b4.z, b4.w};
            #pragma unroll
            for (int i = 0; i < 8; ++i)
                #pragma unroll
                for (int j = 0; j < 4; ++j)
                    acc[i][j] = fmaf(ar[i], br[j], acc[i][j]);
        }
        __syncthreads();
    }
    #pragma unroll
    for (int i = 0; i < 8; ++i) {
        const int row = row0 + ty * 8 + i;
        const int col = n0 + tx * 4;
        float4 o = {acc[i][0], acc[i][1], acc[i][2], acc[i][3]};
        if constexpr (EPI == EPI_VMASK) {
            if (mask[row]) o = make_float4(0.f, 0.f, 0.f, 0.f);
        }
        if constexpr (EPI == EPI_GELU) {
            const float4 b4 = *(const float4*)(bias + col);
            o.x = gelu_exact(o.x + b4.x); o.y = gelu_exact(o.y + b4.y);
            o.z = gelu_exact(o.z + b4.z); o.w = gelu_exact(o.w + b4.w);
        }
        if constexpr (EPI == EPI_FC2) {
            const float4 b4 = *(const float4*)(bias + col);
            const float4 r4 = *(const float4*)(resid + (size_t)row * N + col);
            const float4 l4 = *(const float4*)(lam + col);
            o.x += b4.x + r4.x * l4.x; o.y += b4.y + r4.y * l4.y;
            o.z += b4.z + r4.z * l4.z; o.w += b4.w + r4.w * l4.w;
        }
        *(float4*)(out + (size_t)row * N + col) = o;
    }
}

// ======================= fp32 flash attention =======================
// grid (S/64, H, B), 256 threads. Q-tile 64 rows in registers (4 lanes/row),
// K/V tiles 64x64 in LDS (stride 68 to spread banks). Online softmax.
__global__ __launch_bounds__(256)
void flash_attn_k(const float* __restrict__ q, const float* __restrict__ k,
                  const float* __restrict__ v, const int* __restrict__ mask,
                  const float* __restrict__ gamma, float* __restrict__ out)
{
    __shared__ float Ks[64][68];
    __shared__ float Vs[64][68];
    __shared__ float Ps[64][68];
    const int t  = threadIdx.x;
    const int b  = blockIdx.z, h = blockIdx.y, q0 = blockIdx.x * 64;
    const int r  = t >> 2;            // row this thread works on (0..63)
    const int qt = t & 3;             // quarter
    const int cbase = qt * 16;        // score-col / dh slice
    const int lr = t >> 2, ld = (t & 3) * 16;   // staging indices

    // stage Q tile into Ps, scaled by 1/sqrt(DH), then pull own row to registers
    {
        const float* qp = q + (size_t)(b * SEQ + q0 + lr) * DIM + h * DHEAD + ld;
        #pragma unroll
        for (int jj = 0; jj < 4; ++jj) {
            float4 t4 = *(const float4*)(qp + jj * 4);
            t4.x *= 0.125f; t4.y *= 0.125f; t4.z *= 0.125f; t4.w *= 0.125f;
            *(float4*)(&Ps[lr][ld + jj * 4]) = t4;
        }
    }
    __syncthreads();
    float4 qr[16];
    #pragma unroll
    for (int d4 = 0; d4 < 16; ++d4) qr[d4] = *(const float4*)(&Ps[r][d4 * 4]);
    __syncthreads();

    float O[16] = {};
    float mrow = -3.0e38f, lrow = 0.f;

    for (int kt = 0; kt < 16; ++kt) {
        const float* kp = k + (size_t)(b * SEQ + kt * 64 + lr) * DIM + h * DHEAD + ld;
        const float* vp = v + (size_t)(b * SEQ + kt * 64 + lr) * DIM + h * DHEAD + ld;
        #pragma unroll
        for (int jj = 0; jj < 4; ++jj)
            *(float4*)(&Ks[lr][ld + jj * 4]) = *(const float4*)(kp + jj * 4);
        #pragma unroll
        for (int jj = 0; jj < 4; ++jj)
            *(float4*)(&Vs[lr][ld + jj * 4]) = *(const float4*)(vp + jj * 4);
        __syncthreads();

        float s[16];
        #pragma unroll
        for (int i = 0; i < 16; ++i) {
            const int c = cbase + i;
            float4 a = make_float4(0.f, 0.f, 0.f, 0.f);
            #pragma unroll
            for (int d4 = 0; d4 < 16; ++d4) {
                const float4 kv = *(const float4*)(&Ks[c][d4 * 4]);
                a.x = fmaf(qr[d4].x, kv.x, a.x);
                a.y = fmaf(qr[d4].y, kv.y, a.y);
                a.z = fmaf(qr[d4].z, kv.z, a.z);
                a.w = fmaf(qr[d4].w, kv.w, a.w);
            }
            s[i] = a.x + a.y + a.z + a.w;
            if (mask[b * SEQ + kt * 64 + c]) s[i] = -1e9f;
        }
        // row max across this thread's 16 + its 3 partners
        float mt = s[0];
        #pragma unroll
        for (int i = 1; i < 16; ++i) mt = fmaxf(mt, s[i]);
        mt = fmaxf(mt, __shfl_xor(mt, 1, 64));
        mt = fmaxf(mt, __shfl_xor(mt, 2, 64));
        const float mnew  = fmaxf(mrow, mt);
        const float scale = __expf(mrow - mnew);
        float psum = 0.f;
        #pragma unroll
        for (int i = 0; i < 16; ++i) { s[i] = __expf(s[i] - mnew); psum += s[i]; }
        psum += __shfl_xor(psum, 1, 64);
        psum += __shfl_xor(psum, 2, 64);
        lrow = lrow * scale + psum;
        mrow = mnew;
        #pragma unroll
        for (int j = 0; j < 16; ++j) O[j] *= scale;
        #pragma unroll
        for (int i = 0; i < 16; ++i) Ps[r][cbase + i] = s[i];
        __syncthreads();
        // O[r][cbase..cbase+15] += P[r][:] @ V[:, cbase..cbase+15]
        for (int c = 0; c < 64; ++c) {
            const float p = Ps[r][c];
            #pragma unroll
            for (int j4 = 0; j4 < 4; ++j4) {
                const float4 vv = *(const float4*)(&Vs[c][cbase + j4 * 4]);
                O[j4 * 4 + 0] = fmaf(p, vv.x, O[j4 * 4 + 0]);
                O[j4 * 4 + 1] = fmaf(p, vv.y, O[j4 * 4 + 1]);
                O[j4 * 4 + 2] = fmaf(p, vv.z, O[j4 * 4 + 2]);
                O[j4 * 4 + 3] = fmaf(p, vv.w, O[j4 * 4 + 3]);
            }
        }
        __syncthreads();
    }
    const float inv = gamma[h] / lrow;
    float* op = out + (size_t)(b * SEQ + q0 + r) * DIM + h * DHEAD + cbase;
    #pragma unroll
    for (int j4 = 0; j4 < 4; ++j4) {
        float4 o = {O[j4 * 4 + 0] * inv, O[j4 * 4 + 1] * inv,
                    O[j4 * 4 + 2] * inv, O[j4 * 4 + 3] * inv};
        *(float4*)(op + j4 * 4) = o;
    }
}

// ======================= launch =======================
// Workspace budget (ws overflow was the suspected round-1 crash):
//   mask_i : ws + 0        (32 KB, padded to 1 MB)
//   h      : A + 0   MB    LN0 out -> attn out -> fc1 chunk buffer (32 MB)
//   q      : A + 32  MB    Q -> proj                                (32 MB)
//   k      : A + 64  MB    K -> x2 (attn residual out)              (32 MB)
//   v      : A + 96  MB    V -> h2 (pre-fc LN out)                  (32 MB)
// total: 129 MB. FFN runs in 4 row-chunks of 2048 so the fc1 hidden
// activation (chunk: 2048x4096 fp32 = 32 MB) reuses the h region.
extern "C" void kernel_launch(void* const* d_in, const int* in_sizes, int n_in,
                              void* d_out, int out_size, void* d_ws, size_t ws_size,
                              hipStream_t stream)
{
    const float* x       = (const float*)d_in[0];
    const void*  kpm     = d_in[1];
    const float* wq      = (const float*)d_in[2];
    const float* wk      = (const float*)d_in[3];
    const float* wv      = (const float*)d_in[4];
    const float* wo      = (const float*)d_in[5];
    const float* gamma   = (const float*)d_in[6];
    const float* ln_g    = (const float*)d_in[7];
    const float* ln_b    = (const float*)d_in[8];
    const float* ln_fc_g = (const float*)d_in[9];
    const float* ln_fc_b = (const float*)d_in[10];
    const float* w1      = (const float*)d_in[11];
    const float* b1      = (const float*)d_in[12];
    const float* w2      = (const float*)d_in[13];
    const float* b2      = (const float*)d_in[14];
    const float* lam     = (const float*)d_in[15];
    float* out = (float*)d_out;

    char* ws = (char*)d_ws;
    int*   mask_i = (int*)ws;                               // 32 KB used
    float* hbuf   = (float*)(ws + (1 << 20));               // 32 MB
    float* qbuf   = hbuf + (size_t)NROWS * DIM;             // 32 MB
    float* kbuf   = qbuf + (size_t)NROWS * DIM;             // 32 MB
    float* vbuf   = kbuf + (size_t)NROWS * DIM;             // 32 MB

    canon_mask_k<<<NROWS / 256, 256, 0, stream>>>(kpm, mask_i, NROWS);

    // h = LN0(x)
    ln_k<1><<<NROWS, 256, 0, stream>>>(x, ln_g, ln_b, nullptr, hbuf);

    const dim3 gqkv(DIM / 64, NROWS / 128);
    gemm_k<EPI_NONE ><<<gqkv, 256, 0, stream>>>(hbuf, wq, nullptr, qbuf, NROWS, DIM, DIM, nullptr, nullptr, nullptr);
    gemm_k<EPI_NONE ><<<gqkv, 256, 0, stream>>>(hbuf, wk, nullptr, kbuf, NROWS, DIM, DIM, nullptr, nullptr, nullptr);
    gemm_k<EPI_VMASK><<<gqkv, 256, 0, stream>>>(hbuf, wv, nullptr, vbuf, NROWS, DIM, DIM, mask_i, nullptr, nullptr);

    // attn_out (ws * gamma) -> hbuf (h no longer needed)
    const dim3 gattn(SEQ / 64, NHEAD, NBATCH);
    flash_attn_k<<<gattn, 256, 0, stream>>>(qbuf, kbuf, vbuf, mask_i, gamma, hbuf);

    // proj = attn_out @ wo -> qbuf (q dead after attention)
    gemm_k<EPI_NONE><<<gqkv, 256, 0, stream>>>(hbuf, wo, nullptr, qbuf, NROWS, DIM, DIM, nullptr, nullptr, nullptr);
    // x2 = LN1(proj) + x -> kbuf (k dead after attention)
    ln_k<1><<<NROWS, 256, 0, stream>>>(qbuf, ln_g + DIM, ln_b + DIM, x, kbuf);
    // h2 = LN2(x2) -> vbuf (v dead after attention)
    ln_k<1><<<NROWS, 256, 0, stream>>>(kbuf, ln_g + 2 * DIM, ln_b + 2 * DIM, nullptr, vbuf);

    // FFN in 4 row-chunks of 2048; fc1 hidden chunk reuses hbuf (32 MB).
    const int CH = 2048;
    for (int c = 0; c < NROWS / CH; ++c) {
        const size_t ro = (size_t)c * CH;
        const dim3 gfc1(FDIM / 64, CH / 128);
        gemm_k<EPI_GELU><<<gfc1, 256, 0, stream>>>(vbuf + ro * DIM, w1, b1, hbuf,
                                                   CH, DIM, FDIM, nullptr, nullptr, nullptr);
        ln_k<4><<<CH, 256, 0, stream>>>(hbuf, ln_fc_g, ln_fc_b, nullptr, hbuf);
        const dim3 gfc2(DIM / 64, CH / 128);
        gemm_k<EPI_FC2><<<gfc2, 256, 0, stream>>>(hbuf, w2, b2, out + ro * DIM,
                                                  CH, FDIM, DIM, nullptr, kbuf + ro * DIM, lam);
    }
}

// Round 5
// 667.071 us; speedup vs baseline: 7.0961x; 7.0961x over previous
//
#include <hip/hip_runtime.h>
#include <math.h>

typedef _Float16 h_t;
typedef _Float16 h8 __attribute__((ext_vector_type(8)));
typedef _Float16 h4 __attribute__((ext_vector_type(4)));
typedef float    f4 __attribute__((ext_vector_type(4)));
typedef unsigned int u32;

#define SEQ   1024
#define DIM   1024
#define FDIM  4096
#define NB    8
#define NH    16
#define DHD   64
#define NROWS 8192

// async global->LDS, 16B per lane, dest = uniform base + lane*16 (HW rule)
__device__ __forceinline__ void glds16(const void* g, void* l)
{
    __builtin_amdgcn_global_load_lds((const __attribute__((address_space(1))) u32*)g,
                                     (__attribute__((address_space(3))) u32*)l, 16, 0, 0);
}

// ======================= mask canonicalization =======================
__global__ __launch_bounds__(256)
void canon_mask_k(const void* __restrict__ raw, int* __restrict__ outm, int n)
{
    const unsigned int*  w  = (const unsigned int*)raw;
    const unsigned char* cb = (const unsigned char*)raw;
    __shared__ int flag;
    if (threadIdx.x == 0) flag = 0;
    __syncthreads();
    int bad = 0;
    for (int i = threadIdx.x; i < 1024; i += 256)
        if (w[i] > 1u) bad = 1;
    if (bad) flag = 1;
    __syncthreads();
    const bool is_i32 = (flag == 0);
    const int idx = blockIdx.x * 256 + threadIdx.x;
    if (idx < n) outm[idx] = is_i32 ? (w[idx] != 0u) : (cb[idx] != 0);
}

// ======================= weight transpose+convert: W[K][N] f32 -> Wt[N][K] f16 ===
__global__ __launch_bounds__(256)
void wconv_k(const float* __restrict__ W, h_t* __restrict__ Wt, int K, int N)
{
    __shared__ float T[32][33];
    const int t  = threadIdx.x;
    const int k0 = blockIdx.y * 32, n0 = blockIdx.x * 32;
    const int r = t >> 3, c4 = (t & 7) * 4;
    const float4 v = *(const float4*)(W + (size_t)(k0 + r) * N + n0 + c4);
    T[r][c4 + 0] = v.x; T[r][c4 + 1] = v.y; T[r][c4 + 2] = v.z; T[r][c4 + 3] = v.w;
    __syncthreads();
    h4 o = { (h_t)T[c4 + 0][r], (h_t)T[c4 + 1][r], (h_t)T[c4 + 2][r], (h_t)T[c4 + 3][r] };
    *(h4*)(Wt + (size_t)(n0 + r) * K + k0 + c4) = o;
}

// ======================= LayerNorm =======================
__device__ __forceinline__ void block_reduce2(float& s, float& ss)
{
    #pragma unroll
    for (int off = 32; off > 0; off >>= 1) {
        s  += __shfl_down(s,  off, 64);
        ss += __shfl_down(ss, off, 64);
    }
    __shared__ float sh[8];
    const int wid  = threadIdx.x >> 6;
    const int lane = threadIdx.x & 63;
    if (lane == 0) { sh[wid] = s; sh[4 + wid] = ss; }
    __syncthreads();
    s  = sh[0] + sh[1] + sh[2] + sh[3];
    ss = sh[4] + sh[5] + sh[6] + sh[7];
}

// one row of 1024; optional fp32 residual added after LN; fp16 out
template<typename TI, bool RES>
__global__ __launch_bounds__(256)
void ln1024_k(const TI* __restrict__ in, const float* __restrict__ gw,
              const float* __restrict__ bw, const float* __restrict__ res,
              h_t* __restrict__ out)
{
    const size_t base = (size_t)blockIdx.x * 1024;
    const int c = threadIdx.x * 4;
    float v[4];
    if constexpr (sizeof(TI) == 2) {
        h4 x = *(const h4*)(in + base + c);
        v[0] = (float)x[0]; v[1] = (float)x[1]; v[2] = (float)x[2]; v[3] = (float)x[3];
    } else {
        float4 x = *(const float4*)((const float*)in + base + c);
        v[0] = x.x; v[1] = x.y; v[2] = x.z; v[3] = x.w;
    }
    float s = v[0] + v[1] + v[2] + v[3];
    float ss = v[0]*v[0] + v[1]*v[1] + v[2]*v[2] + v[3]*v[3];
    block_reduce2(s, ss);
    const float mean = s * (1.f / 1024.f);
    const float rstd = rsqrtf(ss * (1.f / 1024.f) - mean * mean + 1e-3f);
    const float4 g4 = *(const float4*)(gw + c);
    const float4 b4 = *(const float4*)(bw + c);
    float o[4];
    o[0] = (v[0]-mean)*rstd*g4.x + b4.x; o[1] = (v[1]-mean)*rstd*g4.y + b4.y;
    o[2] = (v[2]-mean)*rstd*g4.z + b4.z; o[3] = (v[3]-mean)*rstd*g4.w + b4.w;
    if constexpr (RES) {
        const float4 r4 = *(const float4*)(res + base + c);
        o[0] += r4.x; o[1] += r4.y; o[2] += r4.z; o[3] += r4.w;
    }
    h4 oh = {(h_t)o[0], (h_t)o[1], (h_t)o[2], (h_t)o[3]};
    *(h4*)(out + base + c) = oh;
}

// in-place LN over 4096 fp16 cols
__global__ __launch_bounds__(256)
void ln4096_k(h_t* __restrict__ buf, const float* __restrict__ gw,
              const float* __restrict__ bw)
{
    const size_t base = (size_t)blockIdx.x * 4096;
    const int t = threadIdx.x;
    float v[16];
    #pragma unroll
    for (int i = 0; i < 2; ++i) {
        h8 x = *(const h8*)(buf + base + (i * 256 + t) * 8);
        #pragma unroll
        for (int j = 0; j < 8; ++j) v[i * 8 + j] = (float)x[j];
    }
    float s = 0.f, ss = 0.f;
    #pragma unroll
    for (int i = 0; i < 16; ++i) { s += v[i]; ss += v[i] * v[i]; }
    block_reduce2(s, ss);
    const float mean = s * (1.f / 4096.f);
    const float rstd = rsqrtf(ss * (1.f / 4096.f) - mean * mean + 1e-3f);
    #pragma unroll
    for (int i = 0; i < 2; ++i) {
        const int c = (i * 256 + t) * 8;
        h8 o;
        #pragma unroll
        for (int j = 0; j < 8; ++j)
            o[j] = (h_t)((v[i*8+j] - mean) * rstd * gw[c + j] + bw[c + j]);
        *(h8*)(buf + base + c) = o;
    }
}

// ======================= fp16 MFMA GEMM =======================
// C[M,N] = A[M,K](f16) @ Wt[N,K](f16)^T, fp32 accum, fused epilogues.
// 128x128 tile, BK=32, 4 waves (2x2), 16x16x32 MFMA.
// LDS rows are 64B; swizzle: phys_slot = logical_slot ^ (((row>>1)&3)<<4).
// Row parity supplies bank-bit 4, the XOR supplies bits 2-3 -> a 16-lane
// ds_read_b128 group spans all 32 banks (2-way = free, m136).
#define GEPI_QK   0   // fp16 out, head-major [b][h][s][dh]
#define GEPI_VT   1   // fp16 out, transposed [b][h][dh][s], masked rows zeroed
#define GEPI_H16  2   // fp16 out, row-major [M][N]
#define GEPI_GELU 3   // fp16 out, gelu(acc + bias)
#define GEPI_FC2  4   // fp32 out, acc + bias + resid(f16)*lam

__device__ __forceinline__ float gelu_exact(float x)
{
    return 0.5f * x * (1.f + erff(x * 0.70710678118654752440f));
}

template<int EPI>
__global__ __launch_bounds__(256, 2)
void hgemm_k(const h_t* __restrict__ A, const h_t* __restrict__ Wt,
             const float* __restrict__ bias, void* __restrict__ outv,
             int M, int K, int N,
             const int* __restrict__ mask, const h_t* __restrict__ resid,
             const float* __restrict__ lam)
{
    __shared__ h_t As[128 * 32];
    __shared__ h_t Bs[128 * 32];
    const int t = threadIdx.x;
    const int wv = t >> 6, lane = t & 63;
    const int m0 = blockIdx.y * 128, n0 = blockIdx.x * 128;
    const int wr = (wv >> 1) * 64, wc = (wv & 1) * 64;
    const int lr = lane & 15, g = lane >> 4;
    const int srow_base = (lane >> 2);          // row within 16-row group
    const int sslot = (lane & 3) * 16;

    f4 acc[4][4] = {};

    for (int k0 = 0; k0 < K; k0 += 32) {
        __syncthreads();
        #pragma unroll
        for (int i = 0; i < 2; ++i) {
            const int rA = (wv * 2 + i) * 16 + srow_base;
            const int swz = ((rA >> 1) & 3) << 4;
            glds16((const char*)A  + (((size_t)(m0 + rA) * K + k0) << 1) + (sslot ^ swz),
                   (char*)As + (wv * 2 + i) * 1024);
            glds16((const char*)Wt + (((size_t)(n0 + rA) * K + k0) << 1) + (sslot ^ swz),
                   (char*)Bs + (wv * 2 + i) * 1024);
        }
        __syncthreads();
        h8 af[4], bf[4];
        #pragma unroll
        for (int mt = 0; mt < 4; ++mt) {
            const int r = wr + mt * 16 + lr;
            af[mt] = *(const h8*)((const char*)As + r * 64 + ((g * 16) ^ (((r >> 1) & 3) << 4)));
        }
        #pragma unroll
        for (int nt = 0; nt < 4; ++nt) {
            const int r = wc + nt * 16 + lr;
            bf[nt] = *(const h8*)((const char*)Bs + r * 64 + ((g * 16) ^ (((r >> 1) & 3) << 4)));
        }
        #pragma unroll
        for (int mt = 0; mt < 4; ++mt)
            #pragma unroll
            for (int nt = 0; nt < 4; ++nt)
                acc[mt][nt] = __builtin_amdgcn_mfma_f32_16x16x32_f16(af[mt], bf[nt], acc[mt][nt], 0, 0, 0);
    }

    #pragma unroll
    for (int mt = 0; mt < 4; ++mt) {
        #pragma unroll
        for (int nt = 0; nt < 4; ++nt) {
            #pragma unroll
            for (int e = 0; e < 4; ++e) {
                const int row = m0 + wr + mt * 16 + g * 4 + e;
                const int col = n0 + wc + nt * 16 + lr;
                float val = acc[mt][nt][e];
                if constexpr (EPI == GEPI_QK) {
                    const int b = row >> 10, s = row & 1023, hh = col >> 6, dd = col & 63;
                    ((h_t*)outv)[(((size_t)(b * NH + hh)) * SEQ + s) * DHD + dd] = (h_t)val;
                } else if constexpr (EPI == GEPI_VT) {
                    if (mask[row]) val = 0.f;
                    const int b = row >> 10, s = row & 1023, hh = col >> 6, dd = col & 63;
                    ((h_t*)outv)[(((size_t)(b * NH + hh)) * DHD + dd) * SEQ + s] = (h_t)val;
                } else if constexpr (EPI == GEPI_H16) {
                    ((h_t*)outv)[(size_t)row * N + col] = (h_t)val;
                } else if constexpr (EPI == GEPI_GELU) {
                    ((h_t*)outv)[(size_t)row * N + col] = (h_t)gelu_exact(val + bias[col]);
                } else {   // GEPI_FC2
                    val += bias[col] + (float)resid[(size_t)row * N + col] * lam[col];
                    ((float*)outv)[(size_t)row * N + col] = val;
                }
            }
        }
    }
}

// ======================= fp16 MFMA flash attention =======================
// grid (S/64, H, B), 256 thr = 4 waves; wave wv owns q rows q0+16*wv..+15.
// Swapped QK^T (S^T): softmax is per-lane for q = lane&15.
// K staged [kv][64] f16; V staged from pre-transposed V^T as [d][kv] f16.
// 128B LDS rows; swizzle phys = logical ^ ((row&7)<<4) -> 2-way on ds_read_b128.
__global__ __launch_bounds__(256)
void attn_k(const h_t* __restrict__ Q, const h_t* __restrict__ K,
            const h_t* __restrict__ Vt, const int* __restrict__ mask,
            const float* __restrict__ gamma, h_t* __restrict__ out)
{
    __shared__ h_t Kt[64 * 64];
    __shared__ h_t Vs[64 * 64];
    __shared__ h_t Pl[4 * 16 * 64];
    __shared__ float madd[64];
    const int t = threadIdx.x, wv = t >> 6, lane = t & 63;
    const int lr = lane & 15, g = lane >> 4;
    const int b = blockIdx.z, h = blockIdx.y, q0 = blockIdx.x * 64;
    const size_t qkbase = ((size_t)(b * NH + h)) * SEQ * DHD;   // [s][dh] head base
    const size_t vbase  = ((size_t)(b * NH + h)) * DHD * SEQ;   // [dh][s] head base

    // Q fragments (B-operand), pre-scaled by 1/sqrt(64)
    h8 qf[2];
    {
        const h_t* qp = Q + qkbase + (size_t)(q0 + wv * 16 + lr) * DHD;
        const h_t sc = (h_t)0.125f;
        qf[0] = *(const h8*)(qp + 8 * g) * sc;
        qf[1] = *(const h8*)(qp + 32 + 8 * g) * sc;
    }

    f4 o[4] = {};
    float mrun = -3.0e38f, lrun = 0.f;
    h_t* pw = Pl + wv * 1024;

    for (int kt = 0; kt < SEQ / 64; ++kt) {
        const int kv0 = kt * 64;
        __syncthreads();
        #pragma unroll
        for (int i = 0; i < 2; ++i) {
            const int r = (wv * 2 + i) * 8 + (lane >> 3);    // 128B rows, 8 rows/call
            const int slot = (lane & 7) * 16;
            glds16((const char*)K  + ((qkbase + (size_t)(kv0 + r) * DHD) << 1) + (slot ^ ((r & 7) << 4)),
                   (char*)Kt + (wv * 2 + i) * 1024);
            glds16((const char*)Vt + ((vbase + (size_t)r * SEQ + kv0) << 1) + (slot ^ ((r & 7) << 4)),
                   (char*)Vs + (wv * 2 + i) * 1024);
        }
        if (t < 64) madd[t] = mask[b * SEQ + kv0 + t] ? -1e9f : 0.f;
        __syncthreads();

        // S^T tiles: [kv 16t][q 16] per wave
        f4 s[4] = {};
        #pragma unroll
        for (int tt = 0; tt < 4; ++tt) {
            #pragma unroll
            for (int c = 0; c < 2; ++c) {
                const int r = tt * 16 + lr;
                h8 kf = *(const h8*)((const char*)Kt + r * 128 + ((c * 64 + g * 16) ^ ((r & 7) << 4)));
                s[tt] = __builtin_amdgcn_mfma_f32_16x16x32_f16(kf, qf[c], s[tt], 0, 0, 0);
            }
        }
        // mask + online softmax (per-lane q = lr)
        float mt_ = -3.0e38f;
        #pragma unroll
        for (int tt = 0; tt < 4; ++tt) {
            f4 ma = *(const f4*)(&madd[tt * 16 + g * 4]);
            s[tt] += ma;
            mt_ = fmaxf(mt_, fmaxf(fmaxf(s[tt][0], s[tt][1]), fmaxf(s[tt][2], s[tt][3])));
        }
        mt_ = fmaxf(mt_, __shfl_xor(mt_, 16, 64));
        mt_ = fmaxf(mt_, __shfl_xor(mt_, 32, 64));
        const float mnew = fmaxf(mrun, mt_);
        const float scl  = __expf(mrun - mnew);
        mrun = mnew;
        float ps = 0.f;
        #pragma unroll
        for (int tt = 0; tt < 4; ++tt) {
            const float p0 = __expf(s[tt][0] - mnew), p1 = __expf(s[tt][1] - mnew);
            const float p2 = __expf(s[tt][2] - mnew), p3 = __expf(s[tt][3] - mnew);
            ps += p0 + p1 + p2 + p3;
            h4 pq = {(h_t)p0, (h_t)p1, (h_t)p2, (h_t)p3};
            *(h4*)((char*)pw + lr * 128 + ((tt * 32 + g * 8) ^ ((lr & 7) << 4))) = pq;
        }
        ps += __shfl_xor(ps, 16, 64);
        ps += __shfl_xor(ps, 32, 64);
        lrun = lrun * scl + ps;

        // rescale O (O rows belong to q=4g+e; fetch that q's scale cross-lane)
        #pragma unroll
        for (int e = 0; e < 4; ++e) {
            const float sce = __shfl(scl, g * 4 + e, 64);
            #pragma unroll
            for (int dt = 0; dt < 4; ++dt) o[dt][e] *= sce;
        }
        // PV: O[q][d] += P[q][kv] @ V[kv][d]
        #pragma unroll
        for (int c = 0; c < 2; ++c) {
            h8 pa = *(const h8*)((const char*)pw + lr * 128 + ((c * 64 + g * 16) ^ ((lr & 7) << 4)));
            #pragma unroll
            for (int dt = 0; dt < 4; ++dt) {
                const int r = dt * 16 + lr;
                h8 vf = *(const h8*)((const char*)Vs + r * 128 + ((c * 64 + g * 16) ^ ((r & 7) << 4)));
                o[dt] = __builtin_amdgcn_mfma_f32_16x16x32_f16(pa, vf, o[dt], 0, 0, 0);
            }
        }
    }
    const float gm = gamma[h];
    #pragma unroll
    for (int e = 0; e < 4; ++e) {
        const float inv = gm / __shfl(lrun, g * 4 + e, 64);
        const int row = q0 + wv * 16 + g * 4 + e;
        #pragma unroll
        for (int dt = 0; dt < 4; ++dt)
            out[(size_t)(b * SEQ + row) * DIM + h * DHD + dt * 16 + lr] = (h_t)(o[dt][e] * inv);
    }
}

// ======================= launch =======================
// ws layout (105 MB total; 129 MB proven safe in round 2):
//   0       mask (1MB pad) | 1MB wqt(2) wkt(2) wvt(2) wot(2) | 9MB w1t(8) | 17MB w2t(8)
//   25MB  A   16MB : h -> attn_out -> h2
//   41MB  Qb  16MB : Q(head-major) -> proj
//   57MB  Kb  16MB : K(head-major) -> fc1-chunk lo
//   73MB  Vb  16MB : V^T          -> fc1-chunk hi
//   89MB  X2  16MB : x2 fp16 (persists to end)
extern "C" void kernel_launch(void* const* d_in, const int* in_sizes, int n_in,
                              void* d_out, int out_size, void* d_ws, size_t ws_size,
                              hipStream_t stream)
{
    const float* x       = (const float*)d_in[0];
    const void*  kpm     = d_in[1];
    const float* wq      = (const float*)d_in[2];
    const float* wk      = (const float*)d_in[3];
    const float* wv      = (const float*)d_in[4];
    const float* wo      = (const float*)d_in[5];
    const float* gamma   = (const float*)d_in[6];
    const float* ln_g    = (const float*)d_in[7];
    const float* ln_b    = (const float*)d_in[8];
    const float* ln_fc_g = (const float*)d_in[9];
    const float* ln_fc_b = (const float*)d_in[10];
    const float* w1      = (const float*)d_in[11];
    const float* b1      = (const float*)d_in[12];
    const float* w2      = (const float*)d_in[13];
    const float* b2      = (const float*)d_in[14];
    const float* lam     = (const float*)d_in[15];
    float* out = (float*)d_out;

    char* ws = (char*)d_ws;
    const size_t MB = 1 << 20;
    int* mask_i = (int*)ws;
    h_t* wqt = (h_t*)(ws + 1  * MB);
    h_t* wkt = (h_t*)(ws + 3  * MB);
    h_t* wvt = (h_t*)(ws + 5  * MB);
    h_t* wot = (h_t*)(ws + 7  * MB);
    h_t* w1t = (h_t*)(ws + 9  * MB);
    h_t* w2t = (h_t*)(ws + 17 * MB);
    h_t* bufA = (h_t*)(ws + 25 * MB);
    h_t* bufQ = (h_t*)(ws + 41 * MB);
    h_t* bufK = (h_t*)(ws + 57 * MB);   // also fc1 chunk (32MB spanning K+V)
    h_t* bufV = (h_t*)(ws + 73 * MB);
    h_t* bufX2 = (h_t*)(ws + 89 * MB);

    canon_mask_k<<<NROWS / 256, 256, 0, stream>>>(kpm, mask_i, NROWS);

    wconv_k<<<dim3(32, 32),  256, 0, stream>>>(wq, wqt, DIM, DIM);
    wconv_k<<<dim3(32, 32),  256, 0, stream>>>(wk, wkt, DIM, DIM);
    wconv_k<<<dim3(32, 32),  256, 0, stream>>>(wv, wvt, DIM, DIM);
    wconv_k<<<dim3(32, 32),  256, 0, stream>>>(wo, wot, DIM, DIM);
    wconv_k<<<dim3(128, 32), 256, 0, stream>>>(w1, w1t, DIM, FDIM);
    wconv_k<<<dim3(32, 128), 256, 0, stream>>>(w2, w2t, FDIM, DIM);

    // h = LN0(x) -> A (fp16)
    ln1024_k<float, false><<<NROWS, 256, 0, stream>>>(x, ln_g, ln_b, nullptr, bufA);

    const dim3 gqkv(DIM / 128, NROWS / 128);
    hgemm_k<GEPI_QK><<<gqkv, 256, 0, stream>>>(bufA, wqt, nullptr, bufQ, NROWS, DIM, DIM, nullptr, nullptr, nullptr);
    hgemm_k<GEPI_QK><<<gqkv, 256, 0, stream>>>(bufA, wkt, nullptr, bufK, NROWS, DIM, DIM, nullptr, nullptr, nullptr);
    hgemm_k<GEPI_VT><<<gqkv, 256, 0, stream>>>(bufA, wvt, nullptr, bufV, NROWS, DIM, DIM, mask_i, nullptr, nullptr);

    attn_k<<<dim3(SEQ / 64, NH, NB), 256, 0, stream>>>(bufQ, bufK, bufV, mask_i, gamma, bufA);

    // proj = attn_out @ wo -> Qb (fp16 row-major)
    hgemm_k<GEPI_H16><<<gqkv, 256, 0, stream>>>(bufA, wot, nullptr, bufQ, NROWS, DIM, DIM, nullptr, nullptr, nullptr);
    // x2 = LN1(proj) + x -> X2 (fp16)
    ln1024_k<h_t, true><<<NROWS, 256, 0, stream>>>(bufQ, ln_g + DIM, ln_b + DIM, x, bufX2);
    // h2 = LN2(x2) -> A (fp16)
    ln1024_k<h_t, false><<<NROWS, 256, 0, stream>>>(bufX2, ln_g + 2 * DIM, ln_b + 2 * DIM, nullptr, bufA);

    // FFN, 2 chunks of 4096 rows (fc1 chunk = 32MB in bufK..bufV)
    const int CH = 4096;
    for (int c = 0; c < NROWS / CH; ++c) {
        const size_t ro = (size_t)c * CH;
        hgemm_k<GEPI_GELU><<<dim3(FDIM / 128, CH / 128), 256, 0, stream>>>(
            bufA + ro * DIM, w1t, b1, bufK, CH, DIM, FDIM, nullptr, nullptr, nullptr);
        ln4096_k<<<CH, 256, 0, stream>>>(bufK, ln_fc_g, ln_fc_b);
        hgemm_k<GEPI_FC2><<<dim3(DIM / 128, CH / 128), 256, 0, stream>>>(
            bufK, w2t, b2, out + ro * DIM, CH, FDIM, DIM, nullptr, bufX2 + ro * DIM, lam);
    }
}

// Round 8
// 637.613 us; speedup vs baseline: 7.4240x; 1.0462x over previous
//
#include <hip/hip_runtime.h>
#include <math.h>

typedef _Float16 h_t;
typedef _Float16 h8 __attribute__((ext_vector_type(8)));
typedef _Float16 h4 __attribute__((ext_vector_type(4)));
typedef float    f4 __attribute__((ext_vector_type(4)));
typedef unsigned int u32;

#define SEQ   1024
#define DIM   1024
#define FDIM  4096
#define NB    8
#define NH    16
#define DHD   64
#define NROWS 8192

// async global->LDS, 16B per lane, dest = uniform base + lane*16 (HW rule)
__device__ __forceinline__ void glds16(const void* g, void* l)
{
    __builtin_amdgcn_global_load_lds((const __attribute__((address_space(1))) u32*)g,
                                     (__attribute__((address_space(3))) u32*)l, 16, 0, 0);
}

// ======================= mask canonicalization =======================
__global__ __launch_bounds__(256)
void canon_mask_k(const void* __restrict__ raw, int* __restrict__ outm, int n)
{
    const unsigned int*  w  = (const unsigned int*)raw;
    const unsigned char* cb = (const unsigned char*)raw;
    __shared__ int flag;
    if (threadIdx.x == 0) flag = 0;
    __syncthreads();
    int bad = 0;
    for (int i = threadIdx.x; i < 1024; i += 256)
        if (w[i] > 1u) bad = 1;
    if (bad) flag = 1;
    __syncthreads();
    const bool is_i32 = (flag == 0);
    const int idx = blockIdx.x * 256 + threadIdx.x;
    if (idx < n) outm[idx] = is_i32 ? (w[idx] != 0u) : (cb[idx] != 0);
}

// ======================= weight transpose+convert: W[K][N] f32 -> Wt[N][K] f16 ===
__global__ __launch_bounds__(256)
void wconv_k(const float* __restrict__ W, h_t* __restrict__ Wt, int K, int N)
{
    __shared__ float T[32][33];
    const int t  = threadIdx.x;
    const int k0 = blockIdx.y * 32, n0 = blockIdx.x * 32;
    const int r = t >> 3, c4 = (t & 7) * 4;
    const float4 v = *(const float4*)(W + (size_t)(k0 + r) * N + n0 + c4);
    T[r][c4 + 0] = v.x; T[r][c4 + 1] = v.y; T[r][c4 + 2] = v.z; T[r][c4 + 3] = v.w;
    __syncthreads();
    h4 o = { (h_t)T[c4 + 0][r], (h_t)T[c4 + 1][r], (h_t)T[c4 + 2][r], (h_t)T[c4 + 3][r] };
    *(h4*)(Wt + (size_t)(n0 + r) * K + k0 + c4) = o;
}

// ======================= LayerNorm =======================
__device__ __forceinline__ void block_reduce2(float& s, float& ss)
{
    #pragma unroll
    for (int off = 32; off > 0; off >>= 1) {
        s  += __shfl_down(s,  off, 64);
        ss += __shfl_down(ss, off, 64);
    }
    __shared__ float sh[8];
    const int wid  = threadIdx.x >> 6;
    const int lane = threadIdx.x & 63;
    if (lane == 0) { sh[wid] = s; sh[4 + wid] = ss; }
    __syncthreads();
    s  = sh[0] + sh[1] + sh[2] + sh[3];
    ss = sh[4] + sh[5] + sh[6] + sh[7];
}

// one row of 1024 fp32 in; fp16 out (LN0)
__global__ __launch_bounds__(256)
void ln1024_k(const float* __restrict__ in, const float* __restrict__ gw,
              const float* __restrict__ bw, h_t* __restrict__ out)
{
    const size_t base = (size_t)blockIdx.x * 1024;
    const int c = threadIdx.x * 4;
    float4 xv = *(const float4*)(in + base + c);
    float v[4] = {xv.x, xv.y, xv.z, xv.w};
    float s = v[0] + v[1] + v[2] + v[3];
    float ss = v[0]*v[0] + v[1]*v[1] + v[2]*v[2] + v[3]*v[3];
    block_reduce2(s, ss);
    const float mean = s * (1.f / 1024.f);
    const float rstd = rsqrtf(ss * (1.f / 1024.f) - mean * mean + 1e-3f);
    const float4 g4 = *(const float4*)(gw + c);
    const float4 b4 = *(const float4*)(bw + c);
    h4 oh = {(h_t)((v[0]-mean)*rstd*g4.x + b4.x), (h_t)((v[1]-mean)*rstd*g4.y + b4.y),
             (h_t)((v[2]-mean)*rstd*g4.z + b4.z), (h_t)((v[3]-mean)*rstd*g4.w + b4.w)};
    *(h4*)(out + base + c) = oh;
}

// fused: x2 = LN1(proj)+x ; h2 = LN2(x2). One row/block.
__global__ __launch_bounds__(256)
void ln_fuse_k(const h_t* __restrict__ proj, const float* __restrict__ x,
               const float* __restrict__ g1, const float* __restrict__ b1w,
               const float* __restrict__ g2, const float* __restrict__ b2w,
               h_t* __restrict__ x2out, h_t* __restrict__ h2out)
{
    const size_t base = (size_t)blockIdx.x * 1024;
    const int c = threadIdx.x * 4;
    h4 p = *(const h4*)(proj + base + c);
    float v[4] = {(float)p[0], (float)p[1], (float)p[2], (float)p[3]};
    float s = v[0]+v[1]+v[2]+v[3];
    float ss = v[0]*v[0]+v[1]*v[1]+v[2]*v[2]+v[3]*v[3];
    block_reduce2(s, ss);
    {
        const float mean = s * (1.f/1024.f);
        const float rstd = rsqrtf(ss * (1.f/1024.f) - mean*mean + 1e-3f);
        const float4 g4 = *(const float4*)(g1 + c);
        const float4 b4 = *(const float4*)(b1w + c);
        const float4 r4 = *(const float4*)(x + base + c);
        v[0] = (v[0]-mean)*rstd*g4.x + b4.x + r4.x;
        v[1] = (v[1]-mean)*rstd*g4.y + b4.y + r4.y;
        v[2] = (v[2]-mean)*rstd*g4.z + b4.z + r4.z;
        v[3] = (v[3]-mean)*rstd*g4.w + b4.w + r4.w;
    }
    h4 x2h = {(h_t)v[0], (h_t)v[1], (h_t)v[2], (h_t)v[3]};
    *(h4*)(x2out + base + c) = x2h;
    __syncthreads();                       // protect shared scratch reuse
    float s2 = v[0]+v[1]+v[2]+v[3];
    float ss2 = v[0]*v[0]+v[1]*v[1]+v[2]*v[2]+v[3]*v[3];
    block_reduce2(s2, ss2);
    const float mean = s2 * (1.f/1024.f);
    const float rstd = rsqrtf(ss2 * (1.f/1024.f) - mean*mean + 1e-3f);
    const float4 g4 = *(const float4*)(g2 + c);
    const float4 b4 = *(const float4*)(b2w + c);
    h4 oh = {(h_t)((v[0]-mean)*rstd*g4.x + b4.x), (h_t)((v[1]-mean)*rstd*g4.y + b4.y),
             (h_t)((v[2]-mean)*rstd*g4.z + b4.z), (h_t)((v[3]-mean)*rstd*g4.w + b4.w)};
    *(h4*)(h2out + base + c) = oh;
}

// in-place LN over 4096 fp16 cols
__global__ __launch_bounds__(256)
void ln4096_k(h_t* __restrict__ buf, const float* __restrict__ gw,
              const float* __restrict__ bw)
{
    const size_t base = (size_t)blockIdx.x * 4096;
    const int t = threadIdx.x;
    float v[16];
    #pragma unroll
    for (int i = 0; i < 2; ++i) {
        h8 x = *(const h8*)(buf + base + (i * 256 + t) * 8);
        #pragma unroll
        for (int j = 0; j < 8; ++j) v[i * 8 + j] = (float)x[j];
    }
    float s = 0.f, ss = 0.f;
    #pragma unroll
    for (int i = 0; i < 16; ++i) { s += v[i]; ss += v[i] * v[i]; }
    block_reduce2(s, ss);
    const float mean = s * (1.f / 4096.f);
    const float rstd = rsqrtf(ss * (1.f / 4096.f) - mean * mean + 1e-3f);
    #pragma unroll
    for (int i = 0; i < 2; ++i) {
        const int c = (i * 256 + t) * 8;
        h8 o;
        #pragma unroll
        for (int j = 0; j < 8; ++j)
            o[j] = (h_t)((v[i*8+j] - mean) * rstd * gw[c + j] + bw[c + j]);
        *(h8*)(buf + base + c) = o;
    }
}

// ======================= fp16 MFMA GEMM =======================
// C[M,N] = A[M,K](f16) @ Wt[N,K](f16)^T, fp32 accum, fused epilogues.
// 128x128 tile, BK=64, 4 waves (2x2), 16x16x32 MFMA, 32 KB LDS.
// 128B LDS rows; involution: phys_slot = logical_slot ^ ((row&7)<<4);
// staging uses linear dest + inverse-swizzled global source (both sides, #21).
#define GEPI_QKV  0   // fp16 Q,K head-major + V^T (masked rows zeroed)
#define GEPI_H16  2   // fp16 out, row-major [M][N]
#define GEPI_GELU 3   // fp16 out, gelu(acc + bias)
#define GEPI_FC2  4   // fp32 out, acc + bias + resid(f16)*lam

__device__ __forceinline__ float gelu_exact(float x)
{
    return 0.5f * x * (1.f + erff(x * 0.70710678118654752440f));
}

template<int EPI>
__global__ __launch_bounds__(256, 2)
void hgemm_k(const h_t* __restrict__ A, const h_t* __restrict__ Wt,
             const float* __restrict__ bias, void* __restrict__ outv,
             int M, int K, int N,
             const int* __restrict__ mask, const h_t* __restrict__ resid,
             const float* __restrict__ lam, h_t* __restrict__ out2,
             h_t* __restrict__ out3)
{
    __shared__ h_t As[128 * 64];
    __shared__ h_t Bs[128 * 64];
    const int t = threadIdx.x;
    const int wv = t >> 6, lane = t & 63;

    // bijective XCD-aware remap (m204)
    int bx, by;
    {
        const int nwg = gridDim.x * gridDim.y;
        int wg = blockIdx.y * gridDim.x + blockIdx.x;
        const int xcd = wg & 7, rest = wg >> 3;
        const int q = nwg >> 3, r = nwg & 7;
        wg = (xcd < r ? xcd * (q + 1) : r * (q + 1) + (xcd - r) * q) + rest;
        bx = wg % gridDim.x; by = wg / gridDim.x;
    }
    const int m0 = by * 128, n0 = bx * 128;
    const int wr = (wv >> 1) * 64, wc = (wv & 1) * 64;
    const int lr = lane & 15, g = lane >> 4;
    const int sr = lane >> 3;              // staging row-in-8
    const int sslot = (lane & 7) * 16;
    const int sswz = sr << 4;              // (r&7)<<4 with r%8 == sr

    f4 acc[4][4] = {};

    for (int k0 = 0; k0 < K; k0 += 64) {
        __syncthreads();
        #pragma unroll
        for (int j = 0; j < 4; ++j) {
            const int r = j * 32 + wv * 8 + sr;
            glds16((const char*)A  + (((size_t)(m0 + r) * K + k0) << 1) + (sslot ^ sswz),
                   (char*)As + j * 4096 + wv * 1024);
            glds16((const char*)Wt + (((size_t)(n0 + r) * K + k0) << 1) + (sslot ^ sswz),
                   (char*)Bs + j * 4096 + wv * 1024);
        }
        __syncthreads();
        #pragma unroll
        for (int kk = 0; kk < 2; ++kk) {
            h8 af[4], bf[4];
            #pragma unroll
            for (int mt = 0; mt < 4; ++mt) {
                const int r = wr + mt * 16 + lr;
                af[mt] = *(const h8*)((const char*)As + r * 128 + ((kk * 64 + g * 16) ^ ((lr & 7) << 4)));
            }
            #pragma unroll
            for (int nt = 0; nt < 4; ++nt) {
                const int r = wc + nt * 16 + lr;
                bf[nt] = *(const h8*)((const char*)Bs + r * 128 + ((kk * 64 + g * 16) ^ ((lr & 7) << 4)));
            }
            #pragma unroll
            for (int mt = 0; mt < 4; ++mt)
                #pragma unroll
                for (int nt = 0; nt < 4; ++nt)
                    acc[mt][nt] = __builtin_amdgcn_mfma_f32_16x16x32_f16(af[mt], bf[nt], acc[mt][nt], 0, 0, 0);
        }
    }

    #pragma unroll
    for (int mt = 0; mt < 4; ++mt) {
        #pragma unroll
        for (int nt = 0; nt < 4; ++nt) {
            #pragma unroll
            for (int e = 0; e < 4; ++e) {
                const int row = m0 + wr + mt * 16 + g * 4 + e;
                const int col = n0 + wc + nt * 16 + lr;
                float val = acc[mt][nt][e];
                if constexpr (EPI == GEPI_QKV) {
                    const int matm = col >> 10;           // uniform per nt
                    const int cc = col & 1023;
                    const int b = row >> 10, s = row & 1023;
                    const int hh = cc >> 6, dd = cc & 63;
                    if (matm == 0)
                        ((h_t*)outv)[(((size_t)(b * NH + hh)) * SEQ + s) * DHD + dd] = (h_t)val;
                    else if (matm == 1)
                        out2[(((size_t)(b * NH + hh)) * SEQ + s) * DHD + dd] = (h_t)val;
                    else {
                        if (mask[row]) val = 0.f;
                        out3[(((size_t)(b * NH + hh)) * DHD + dd) * SEQ + s] = (h_t)val;
                    }
                } else if constexpr (EPI == GEPI_H16) {
                    ((h_t*)outv)[(size_t)row * N + col] = (h_t)val;
                } else if constexpr (EPI == GEPI_GELU) {
                    ((h_t*)outv)[(size_t)row * N + col] = (h_t)gelu_exact(val + bias[col]);
                } else {   // GEPI_FC2
                    val += bias[col] + (float)resid[(size_t)row * N + col] * lam[col];
                    ((float*)outv)[(size_t)row * N + col] = val;
                }
            }
        }
    }
}

// ======================= fp16 MFMA flash attention =======================
// grid (S/64, H, B), 4 waves; wave wv owns q rows q0+16*wv..+15.
// Swapped QK^T; per-lane softmax for q=lane&15; T13 defer-max (THR=8).
// All LDS offsets are kt-invariant -> precomputed once (VGPR budget via lb(256,3)).
__global__ __launch_bounds__(256, 3)
void attn_k(const h_t* __restrict__ Q, const h_t* __restrict__ K,
            const h_t* __restrict__ Vt, const int* __restrict__ mask,
            const float* __restrict__ gamma, h_t* __restrict__ out)
{
    __shared__ h_t Kt[64 * 64];
    __shared__ h_t Vs[64 * 64];
    __shared__ h_t Pl[4 * 16 * 64];
    __shared__ float madd[64];
    const int t = threadIdx.x, wv = t >> 6, lane = t & 63;
    const int lr = lane & 15, g = lane >> 4;
    const int b = blockIdx.z, h = blockIdx.y, q0 = blockIdx.x * 64;
    const size_t qkbase = ((size_t)(b * NH + h)) * SEQ * DHD;   // [s][dh]
    const size_t vbase  = ((size_t)(b * NH + h)) * DHD * SEQ;   // [dh][s]

    // Q fragments (B-operand), pre-scaled by 1/sqrt(64)
    h8 qf[2];
    {
        const h_t* qp = Q + qkbase + (size_t)(q0 + wv * 16 + lr) * DHD;
        const h_t sc = (h_t)0.125f;
        qf[0] = *(const h8*)(qp + 8 * g) * sc;
        qf[1] = *(const h8*)(qp + 32 + 8 * g) * sc;
    }

    // kt-invariant LDS byte offsets
    int koff[4][2], poff[4], paoff[2];
    #pragma unroll
    for (int tt = 0; tt < 4; ++tt) {
        const int r = tt * 16 + lr;
        const int sw = (r & 7) << 4;
        koff[tt][0] = r * 128 + ((g * 16) ^ sw);
        koff[tt][1] = r * 128 + ((64 + g * 16) ^ sw);
        poff[tt] = lr * 128 + (((tt * 32 + g * 8)) ^ ((lr & 7) << 4));
    }
    #pragma unroll
    for (int c = 0; c < 2; ++c)
        paoff[c] = lr * 128 + ((c * 64 + g * 16) ^ ((lr & 7) << 4));

    const int sgr = lane >> 3;            // staging
    const int sgslot = (lane & 7) * 16;
    const int sgswz = sgr << 4;

    f4 o[4] = {};
    float mrun = -3.0e38f, lrun = 0.f;
    h_t* pw = Pl + wv * 1024;

    for (int kt = 0; kt < SEQ / 64; ++kt) {
        const int kv0 = kt * 64;
        __syncthreads();
        #pragma unroll
        for (int i = 0; i < 2; ++i) {
            const int r = (wv * 2 + i) * 8 + sgr;
            glds16((const char*)K  + ((qkbase + (size_t)(kv0 + r) * DHD) << 1) + (sgslot ^ sgswz),
                   (char*)Kt + (wv * 2 + i) * 1024);
            glds16((const char*)Vt + ((vbase + (size_t)r * SEQ + kv0) << 1) + (sgslot ^ sgswz),
                   (char*)Vs + (wv * 2 + i) * 1024);
        }
        if (t < 64) madd[t] = mask[b * SEQ + kv0 + t] ? -1e9f : 0.f;
        __syncthreads();

        // S^T tiles: [kv 16t][q 16] per wave
        f4 s[4] = {};
        #pragma unroll
        for (int tt = 0; tt < 4; ++tt)
            #pragma unroll
            for (int c = 0; c < 2; ++c) {
                h8 kf = *(const h8*)((const char*)Kt + koff[tt][c]);
                s[tt] = __builtin_amdgcn_mfma_f32_16x16x32_f16(kf, qf[c], s[tt], 0, 0, 0);
            }
        // mask + online softmax (per-lane q = lr)
        float mt_ = -3.0e38f;
        #pragma unroll
        for (int tt = 0; tt < 4; ++tt) {
            f4 ma = *(const f4*)(&madd[tt * 16 + g * 4]);
            s[tt] += ma;
            mt_ = fmaxf(mt_, fmaxf(fmaxf(s[tt][0], s[tt][1]), fmaxf(s[tt][2], s[tt][3])));
        }
        mt_ = fmaxf(mt_, __shfl_xor(mt_, 16, 64));
        mt_ = fmaxf(mt_, __shfl_xor(mt_, 32, 64));

        const bool skip = __all(mt_ <= mrun + 8.f);   // T13 defer-max
        float scl = 1.f;
        if (!skip) {
            const float mnew = fmaxf(mrun, mt_);
            scl = __expf(mrun - mnew);
            mrun = mnew;
        }
        float ps = 0.f;
        #pragma unroll
        for (int tt = 0; tt < 4; ++tt) {
            const float p0 = __expf(s[tt][0] - mrun), p1 = __expf(s[tt][1] - mrun);
            const float p2 = __expf(s[tt][2] - mrun), p3 = __expf(s[tt][3] - mrun);
            ps += p0 + p1 + p2 + p3;
            h4 pq = {(h_t)p0, (h_t)p1, (h_t)p2, (h_t)p3};
            *(h4*)((char*)pw + poff[tt]) = pq;
        }
        ps += __shfl_xor(ps, 16, 64);
        ps += __shfl_xor(ps, 32, 64);
        if (skip) {
            lrun += ps;
        } else {
            lrun = lrun * scl + ps;
            #pragma unroll
            for (int e = 0; e < 4; ++e) {
                const float sce = __shfl(scl, g * 4 + e, 64);
                #pragma unroll
                for (int dt = 0; dt < 4; ++dt) o[dt][e] *= sce;
            }
        }
        // PV: O[q][d] += P[q][kv] @ V[kv][d]
        #pragma unroll
        for (int c = 0; c < 2; ++c) {
            h8 pa = *(const h8*)((const char*)pw + paoff[c]);
            #pragma unroll
            for (int dt = 0; dt < 4; ++dt) {
                h8 vf = *(const h8*)((const char*)Vs + koff[dt][c]);
                o[dt] = __builtin_amdgcn_mfma_f32_16x16x32_f16(pa, vf, o[dt], 0, 0, 0);
            }
        }
    }
    const float gm = gamma[h];
    #pragma unroll
    for (int e = 0; e < 4; ++e) {
        const float inv = gm / __shfl(lrun, g * 4 + e, 64);
        const int row = q0 + wv * 16 + g * 4 + e;
        #pragma unroll
        for (int dt = 0; dt < 4; ++dt)
            out[(size_t)(b * SEQ + row) * DIM + h * DHD + dt * 16 + lr] = (h_t)(o[dt][e] * inv);
    }
}

// ======================= launch =======================
// ws layout (105 MB total; 129 MB proven safe):
//   0 mask(1MB) | 1MB wqkv_t [3072][1024] f16 (6MB) | 7MB wot(2) | 9MB w1t(8) | 17MB w2t(8)
//   25MB  A   : h -> attn_out -> h2
//   41MB  Qb  : Q(head-major) -> proj
//   57MB  Kb  : K(head-major) -> fc1-chunk (32MB spans Kb+Vb)
//   73MB  Vb  : V^T
//   89MB  X2  : x2 fp16 (lives to end)
extern "C" void kernel_launch(void* const* d_in, const int* in_sizes, int n_in,
                              void* d_out, int out_size, void* d_ws, size_t ws_size,
                              hipStream_t stream)
{
    const float* x       = (const float*)d_in[0];
    const void*  kpm     = d_in[1];
    const float* wq      = (const float*)d_in[2];
    const float* wk      = (const float*)d_in[3];
    const float* wv      = (const float*)d_in[4];
    const float* wo      = (const float*)d_in[5];
    const float* gamma   = (const float*)d_in[6];
    const float* ln_g    = (const float*)d_in[7];
    const float* ln_b    = (const float*)d_in[8];
    const float* ln_fc_g = (const float*)d_in[9];
    const float* ln_fc_b = (const float*)d_in[10];
    const float* w1      = (const float*)d_in[11];
    const float* b1      = (const float*)d_in[12];
    const float* w2      = (const float*)d_in[13];
    const float* b2      = (const float*)d_in[14];
    const float* lam     = (const float*)d_in[15];
    float* out = (float*)d_out;

    char* ws = (char*)d_ws;
    const size_t MB = 1 << 20;
    int* mask_i = (int*)ws;
    h_t* wqkvt = (h_t*)(ws + 1  * MB);   // [3072][1024]
    h_t* wqt = wqkvt;
    h_t* wkt = wqkvt + (size_t)1024 * 1024;
    h_t* wvt = wqkvt + (size_t)2048 * 1024;
    h_t* wot = (h_t*)(ws + 7  * MB);
    h_t* w1t = (h_t*)(ws + 9  * MB);
    h_t* w2t = (h_t*)(ws + 17 * MB);
    h_t* bufA = (h_t*)(ws + 25 * MB);
    h_t* bufQ = (h_t*)(ws + 41 * MB);
    h_t* bufK = (h_t*)(ws + 57 * MB);
    h_t* bufV = (h_t*)(ws + 73 * MB);
    h_t* bufX2 = (h_t*)(ws + 89 * MB);

    canon_mask_k<<<NROWS / 256, 256, 0, stream>>>(kpm, mask_i, NROWS);

    wconv_k<<<dim3(32, 32),  256, 0, stream>>>(wq, wqt, DIM, DIM);
    wconv_k<<<dim3(32, 32),  256, 0, stream>>>(wk, wkt, DIM, DIM);
    wconv_k<<<dim3(32, 32),  256, 0, stream>>>(wv, wvt, DIM, DIM);
    wconv_k<<<dim3(32, 32),  256, 0, stream>>>(wo, wot, DIM, DIM);
    wconv_k<<<dim3(128, 32), 256, 0, stream>>>(w1, w1t, DIM, FDIM);
    wconv_k<<<dim3(32, 128), 256, 0, stream>>>(w2, w2t, FDIM, DIM);

    // h = LN0(x) -> A (fp16)
    ln1024_k<<<NROWS, 256, 0, stream>>>(x, ln_g, ln_b, bufA);

    // fused QKV: N=3072
    hgemm_k<GEPI_QKV><<<dim3(3072 / 128, NROWS / 128), 256, 0, stream>>>(
        bufA, wqkvt, nullptr, bufQ, NROWS, DIM, 3072, mask_i, nullptr, nullptr, bufK, bufV);

    attn_k<<<dim3(SEQ / 64, NH, NB), 256, 0, stream>>>(bufQ, bufK, bufV, mask_i, gamma, bufA);

    // proj = attn_out @ wo -> Qb (fp16 row-major)
    hgemm_k<GEPI_H16><<<dim3(DIM / 128, NROWS / 128), 256, 0, stream>>>(
        bufA, wot, nullptr, bufQ, NROWS, DIM, DIM, nullptr, nullptr, nullptr, nullptr, nullptr);

    // x2 = LN1(proj)+x -> X2 ; h2 = LN2(x2) -> A   (fused)
    ln_fuse_k<<<NROWS, 256, 0, stream>>>(bufQ, x, ln_g + DIM, ln_b + DIM,
                                         ln_g + 2 * DIM, ln_b + 2 * DIM, bufX2, bufA);

    // FFN, 2 chunks of 4096 rows (fc1 chunk = 32MB in bufK..bufV)
    const int CH = 4096;
    for (int c = 0; c < NROWS / CH; ++c) {
        const size_t ro = (size_t)c * CH;
        hgemm_k<GEPI_GELU><<<dim3(FDIM / 128, CH / 128), 256, 0, stream>>>(
            bufA + ro * DIM, w1t, b1, bufK, CH, DIM, FDIM, nullptr, nullptr, nullptr, nullptr, nullptr);
        ln4096_k<<<CH, 256, 0, stream>>>(bufK, ln_fc_g, ln_fc_b);
        hgemm_k<GEPI_FC2><<<dim3(DIM / 128, CH / 128), 256, 0, stream>>>(
            bufK, w2t, b2, out + ro * DIM, CH, FDIM, DIM, nullptr, bufX2 + ro * DIM, lam, nullptr, nullptr);
    }
}

// Round 12
// 625.924 us; speedup vs baseline: 7.5626x; 1.0187x over previous
//
#include <hip/hip_runtime.h>
#include <math.h>

typedef _Float16 h_t;
typedef _Float16 h8 __attribute__((ext_vector_type(8)));
typedef _Float16 h4 __attribute__((ext_vector_type(4)));
typedef float    f4 __attribute__((ext_vector_type(4)));
typedef unsigned int u32;

#define SEQ   1024
#define DIM   1024
#define FDIM  4096
#define NB    8
#define NH    16
#define DHD   64
#define NROWS 8192

// async global->LDS, 16B per lane, dest = uniform base + lane*16 (HW rule)
__device__ __forceinline__ void glds16(const void* g, void* l)
{
    __builtin_amdgcn_global_load_lds((const __attribute__((address_space(1))) u32*)g,
                                     (__attribute__((address_space(3))) u32*)l, 16, 0, 0);
}

// ======================= mask canonicalization =======================
__global__ __launch_bounds__(256)
void canon_mask_k(const void* __restrict__ raw, int* __restrict__ outm, int n)
{
    const unsigned int*  w  = (const unsigned int*)raw;
    const unsigned char* cb = (const unsigned char*)raw;
    __shared__ int flag;
    if (threadIdx.x == 0) flag = 0;
    __syncthreads();
    int bad = 0;
    for (int i = threadIdx.x; i < 1024; i += 256)
        if (w[i] > 1u) bad = 1;
    if (bad) flag = 1;
    __syncthreads();
    const bool is_i32 = (flag == 0);
    const int idx = blockIdx.x * 256 + threadIdx.x;
    if (idx < n) outm[idx] = is_i32 ? (w[idx] != 0u) : (cb[idx] != 0);
}

// ======================= weight transpose+convert: W[K][N] f32 -> Wt[N][K] f16 ===
__device__ __forceinline__ void wconv_body(const float* __restrict__ W, h_t* __restrict__ Wt,
                                           int K, int N, int bx, int by)
{
    __shared__ float T[32][33];
    const int t  = threadIdx.x;
    const int k0 = by * 32, n0 = bx * 32;
    const int r = t >> 3, c4 = (t & 7) * 4;
    const float4 v = *(const float4*)(W + (size_t)(k0 + r) * N + n0 + c4);
    T[r][c4 + 0] = v.x; T[r][c4 + 1] = v.y; T[r][c4 + 2] = v.z; T[r][c4 + 3] = v.w;
    __syncthreads();
    h4 o = { (h_t)T[c4 + 0][r], (h_t)T[c4 + 1][r], (h_t)T[c4 + 2][r], (h_t)T[c4 + 3][r] };
    *(h4*)(Wt + (size_t)(n0 + r) * K + k0 + c4) = o;
}

__global__ __launch_bounds__(256)
void wconv_k(const float* __restrict__ W, h_t* __restrict__ Wt, int K, int N)
{
    wconv_body(W, Wt, K, N, blockIdx.x, blockIdx.y);
}

// 4 square 1024x1024 weights in one launch (z selects)
__global__ __launch_bounds__(256)
void wconv4_k(const float* __restrict__ W0, const float* __restrict__ W1,
              const float* __restrict__ W2, const float* __restrict__ W3,
              h_t* __restrict__ O0, h_t* __restrict__ O1,
              h_t* __restrict__ O2, h_t* __restrict__ O3)
{
    const int z = blockIdx.z;
    const float* W = (z == 0) ? W0 : (z == 1) ? W1 : (z == 2) ? W2 : W3;
    h_t*       Wt = (z == 0) ? O0 : (z == 1) ? O1 : (z == 2) ? O2 : O3;
    wconv_body(W, Wt, DIM, DIM, blockIdx.x, blockIdx.y);
}

// ======================= LayerNorm =======================
__device__ __forceinline__ void block_reduce2(float& s, float& ss)
{
    #pragma unroll
    for (int off = 32; off > 0; off >>= 1) {
        s  += __shfl_down(s,  off, 64);
        ss += __shfl_down(ss, off, 64);
    }
    __shared__ float sh[8];
    const int wid  = threadIdx.x >> 6;
    const int lane = threadIdx.x & 63;
    if (lane == 0) { sh[wid] = s; sh[4 + wid] = ss; }
    __syncthreads();
    s  = sh[0] + sh[1] + sh[2] + sh[3];
    ss = sh[4] + sh[5] + sh[6] + sh[7];
}

// one row of 1024 fp32 in; fp16 out (LN0)
__global__ __launch_bounds__(256)
void ln1024_k(const float* __restrict__ in, const float* __restrict__ gw,
              const float* __restrict__ bw, h_t* __restrict__ out)
{
    const size_t base = (size_t)blockIdx.x * 1024;
    const int c = threadIdx.x * 4;
    float4 xv = *(const float4*)(in + base + c);
    float v[4] = {xv.x, xv.y, xv.z, xv.w};
    float s = v[0] + v[1] + v[2] + v[3];
    float ss = v[0]*v[0] + v[1]*v[1] + v[2]*v[2] + v[3]*v[3];
    block_reduce2(s, ss);
    const float mean = s * (1.f / 1024.f);
    const float rstd = rsqrtf(ss * (1.f / 1024.f) - mean * mean + 1e-3f);
    const float4 g4 = *(const float4*)(gw + c);
    const float4 b4 = *(const float4*)(bw + c);
    h4 oh = {(h_t)((v[0]-mean)*rstd*g4.x + b4.x), (h_t)((v[1]-mean)*rstd*g4.y + b4.y),
             (h_t)((v[2]-mean)*rstd*g4.z + b4.z), (h_t)((v[3]-mean)*rstd*g4.w + b4.w)};
    *(h4*)(out + base + c) = oh;
}

// fused: x2 = LN1(proj)+x ; h2 = LN2(x2). One row/block.
__global__ __launch_bounds__(256)
void ln_fuse_k(const h_t* __restrict__ proj, const float* __restrict__ x,
               const float* __restrict__ g1, const float* __restrict__ b1w,
               const float* __restrict__ g2, const float* __restrict__ b2w,
               h_t* __restrict__ x2out, h_t* __restrict__ h2out)
{
    const size_t base = (size_t)blockIdx.x * 1024;
    const int c = threadIdx.x * 4;
    h4 p = *(const h4*)(proj + base + c);
    float v[4] = {(float)p[0], (float)p[1], (float)p[2], (float)p[3]};
    float s = v[0]+v[1]+v[2]+v[3];
    float ss = v[0]*v[0]+v[1]*v[1]+v[2]*v[2]+v[3]*v[3];
    block_reduce2(s, ss);
    {
        const float mean = s * (1.f/1024.f);
        const float rstd = rsqrtf(ss * (1.f/1024.f) - mean*mean + 1e-3f);
        const float4 g4 = *(const float4*)(g1 + c);
        const float4 b4 = *(const float4*)(b1w + c);
        const float4 r4 = *(const float4*)(x + base + c);
        v[0] = (v[0]-mean)*rstd*g4.x + b4.x + r4.x;
        v[1] = (v[1]-mean)*rstd*g4.y + b4.y + r4.y;
        v[2] = (v[2]-mean)*rstd*g4.z + b4.z + r4.z;
        v[3] = (v[3]-mean)*rstd*g4.w + b4.w + r4.w;
    }
    h4 x2h = {(h_t)v[0], (h_t)v[1], (h_t)v[2], (h_t)v[3]};
    *(h4*)(x2out + base + c) = x2h;
    __syncthreads();                       // protect shared scratch reuse
    float s2 = v[0]+v[1]+v[2]+v[3];
    float ss2 = v[0]*v[0]+v[1]*v[1]+v[2]*v[2]+v[3]*v[3];
    block_reduce2(s2, ss2);
    const float mean = s2 * (1.f/1024.f);
    const float rstd = rsqrtf(ss2 * (1.f/1024.f) - mean*mean + 1e-3f);
    const float4 g4 = *(const float4*)(g2 + c);
    const float4 b4 = *(const float4*)(b2w + c);
    h4 oh = {(h_t)((v[0]-mean)*rstd*g4.x + b4.x), (h_t)((v[1]-mean)*rstd*g4.y + b4.y),
             (h_t)((v[2]-mean)*rstd*g4.z + b4.z), (h_t)((v[3]-mean)*rstd*g4.w + b4.w)};
    *(h4*)(h2out + base + c) = oh;
}

// in-place LN over 4096 fp16 cols
__global__ __launch_bounds__(256)
void ln4096_k(h_t* __restrict__ buf, const float* __restrict__ gw,
              const float* __restrict__ bw)
{
    const size_t base = (size_t)blockIdx.x * 4096;
    const int t = threadIdx.x;
    float v[16];
    #pragma unroll
    for (int i = 0; i < 2; ++i) {
        h8 x = *(const h8*)(buf + base + (i * 256 + t) * 8);
        #pragma unroll
        for (int j = 0; j < 8; ++j) v[i * 8 + j] = (float)x[j];
    }
    float s = 0.f, ss = 0.f;
    #pragma unroll
    for (int i = 0; i < 16; ++i) { s += v[i]; ss += v[i] * v[i]; }
    block_reduce2(s, ss);
    const float mean = s * (1.f / 4096.f);
    const float rstd = rsqrtf(ss * (1.f / 4096.f) - mean * mean + 1e-3f);
    #pragma unroll
    for (int i = 0; i < 2; ++i) {
        const int c = (i * 256 + t) * 8;
        h8 o;
        #pragma unroll
        for (int j = 0; j < 8; ++j)
            o[j] = (h_t)((v[i*8+j] - mean) * rstd * gw[c + j] + bw[c + j]);
        *(h8*)(buf + base + c) = o;
    }
}

// ======================= fp16 MFMA GEMM (double-buffered) =======================
// C[M,N] = A[M,K](f16) @ Wt[N,K](f16)^T, fp32 accum, fused epilogues.
// 128x128 tile, BK=64, 4 waves (2x2), 16x16x32 MFMA, 64 KB LDS (2 buffers).
// T3-minimum pipeline: STAGE(t+1) issued BEFORE compute(t); single
// __syncthreads per K-step drains the in-flight loads after compute hides them.
// 128B LDS rows; involution: phys_slot = logical_slot ^ ((row&7)<<4);
// staging = linear dest + inverse-swizzled global source (both sides, #21).
#define GEPI_QKV  0   // fp16 Q,K head-major + V^T (masked rows zeroed)
#define GEPI_H16  2   // fp16 out, row-major [M][N]
#define GEPI_GELU 3   // fp16 out, gelu(acc + bias)
#define GEPI_FC2  4   // fp32 out, acc + bias + resid(f16)*lam

__device__ __forceinline__ float gelu_exact(float x)
{
    return 0.5f * x * (1.f + erff(x * 0.70710678118654752440f));
}

template<int EPI>
__global__ __launch_bounds__(256, 2)
void hgemm_k(const h_t* __restrict__ A, const h_t* __restrict__ Wt,
             const float* __restrict__ bias, void* __restrict__ outv,
             int M, int K, int N,
             const int* __restrict__ mask, const h_t* __restrict__ resid,
             const float* __restrict__ lam, h_t* __restrict__ out2,
             h_t* __restrict__ out3)
{
    __shared__ h_t As[2][128 * 64];
    __shared__ h_t Bs[2][128 * 64];
    const int t = threadIdx.x;
    const int wv = t >> 6, lane = t & 63;

    // bijective XCD-aware remap (m204)
    int bx, by;
    {
        const int nwg = gridDim.x * gridDim.y;
        int wg = blockIdx.y * gridDim.x + blockIdx.x;
        const int xcd = wg & 7, rest = wg >> 3;
        const int q = nwg >> 3, r = nwg & 7;
        wg = (xcd < r ? xcd * (q + 1) : r * (q + 1) + (xcd - r) * q) + rest;
        bx = wg % gridDim.x; by = wg / gridDim.x;
    }
    const int m0 = by * 128, n0 = bx * 128;
    const int wr = (wv >> 1) * 64, wc = (wv & 1) * 64;
    const int lr = lane & 15, g = lane >> 4;
    const int sr = lane >> 3;              // staging row-in-8
    const int sslot = (lane & 7) * 16;
    const int sswz = sr << 4;              // (r&7)<<4 with r%8 == sr

    // issue one k-tile's staging into buffer `which`
    auto STAGE = [&](int which, int k0) {
        #pragma unroll
        for (int j = 0; j < 4; ++j) {
            const int r = j * 32 + wv * 8 + sr;
            glds16((const char*)A  + (((size_t)(m0 + r) * K + k0) << 1) + (sslot ^ sswz),
                   (char*)As[which] + j * 4096 + wv * 1024);
            glds16((const char*)Wt + (((size_t)(n0 + r) * K + k0) << 1) + (sslot ^ sswz),
                   (char*)Bs[which] + j * 4096 + wv * 1024);
        }
    };

    f4 acc[4][4] = {};

    STAGE(0, 0);                            // prologue
    int cur = 0;
    for (int k0 = 0; k0 < K; k0 += 64) {
        __syncthreads();                    // drains cur's loads (+ prev reads)
        if (k0 + 64 < K) STAGE(cur ^ 1, k0 + 64);   // issue next, in flight
        #pragma unroll
        for (int kk = 0; kk < 2; ++kk) {
            h8 af[4], bf[4];
            #pragma unroll
            for (int mt = 0; mt < 4; ++mt) {
                const int r = wr + mt * 16 + lr;
                af[mt] = *(const h8*)((const char*)As[cur] + r * 128 + ((kk * 64 + g * 16) ^ ((lr & 7) << 4)));
            }
            #pragma unroll
            for (int nt = 0; nt < 4; ++nt) {
                const int r = wc + nt * 16 + lr;
                bf[nt] = *(const h8*)((const char*)Bs[cur] + r * 128 + ((kk * 64 + g * 16) ^ ((lr & 7) << 4)));
            }
            #pragma unroll
            for (int mt = 0; mt < 4; ++mt)
                #pragma unroll
                for (int nt = 0; nt < 4; ++nt)
                    acc[mt][nt] = __builtin_amdgcn_mfma_f32_16x16x32_f16(af[mt], bf[nt], acc[mt][nt], 0, 0, 0);
        }
        cur ^= 1;
    }

    #pragma unroll
    for (int mt = 0; mt < 4; ++mt) {
        #pragma unroll
        for (int nt = 0; nt < 4; ++nt) {
            #pragma unroll
            for (int e = 0; e < 4; ++e) {
                const int row = m0 + wr + mt * 16 + g * 4 + e;
                const int col = n0 + wc + nt * 16 + lr;
                float val = acc[mt][nt][e];
                if constexpr (EPI == GEPI_QKV) {
                    const int matm = col >> 10;           // uniform per nt
                    const int cc = col & 1023;
                    const int b = row >> 10, s = row & 1023;
                    const int hh = cc >> 6, dd = cc & 63;
                    if (matm == 0)
                        ((h_t*)outv)[(((size_t)(b * NH + hh)) * SEQ + s) * DHD + dd] = (h_t)val;
                    else if (matm == 1)
                        out2[(((size_t)(b * NH + hh)) * SEQ + s) * DHD + dd] = (h_t)val;
                    else {
                        if (mask[row]) val = 0.f;
                        out3[(((size_t)(b * NH + hh)) * DHD + dd) * SEQ + s] = (h_t)val;
                    }
                } else if constexpr (EPI == GEPI_H16) {
                    ((h_t*)outv)[(size_t)row * N + col] = (h_t)val;
                } else if constexpr (EPI == GEPI_GELU) {
                    ((h_t*)outv)[(size_t)row * N + col] = (h_t)gelu_exact(val + bias[col]);
                } else {   // GEPI_FC2
                    val += bias[col] + (float)resid[(size_t)row * N + col] * lam[col];
                    ((float*)outv)[(size_t)row * N + col] = val;
                }
            }
        }
    }
}

// ======================= fp16 MFMA flash attention =======================
// grid (S/64, H, B), 4 waves; wave wv owns q rows q0+16*wv..+15.
// Swapped QK^T; per-lane softmax for q=lane&15; T13 defer-max (THR=8).
__global__ __launch_bounds__(256, 3)
void attn_k(const h_t* __restrict__ Q, const h_t* __restrict__ K,
            const h_t* __restrict__ Vt, const int* __restrict__ mask,
            const float* __restrict__ gamma, h_t* __restrict__ out)
{
    __shared__ h_t Kt[64 * 64];
    __shared__ h_t Vs[64 * 64];
    __shared__ h_t Pl[4 * 16 * 64];
    __shared__ float madd[64];
    const int t = threadIdx.x, wv = t >> 6, lane = t & 63;
    const int lr = lane & 15, g = lane >> 4;
    const int b = blockIdx.z, h = blockIdx.y, q0 = blockIdx.x * 64;
    const size_t qkbase = ((size_t)(b * NH + h)) * SEQ * DHD;   // [s][dh]
    const size_t vbase  = ((size_t)(b * NH + h)) * DHD * SEQ;   // [dh][s]

    // Q fragments (B-operand), pre-scaled by 1/sqrt(64)
    h8 qf[2];
    {
        const h_t* qp = Q + qkbase + (size_t)(q0 + wv * 16 + lr) * DHD;
        const h_t sc = (h_t)0.125f;
        qf[0] = *(const h8*)(qp + 8 * g) * sc;
        qf[1] = *(const h8*)(qp + 32 + 8 * g) * sc;
    }

    // kt-invariant LDS byte offsets
    int koff[4][2], poff[4], paoff[2];
    #pragma unroll
    for (int tt = 0; tt < 4; ++tt) {
        const int r = tt * 16 + lr;
        const int sw = (r & 7) << 4;
        koff[tt][0] = r * 128 + ((g * 16) ^ sw);
        koff[tt][1] = r * 128 + ((64 + g * 16) ^ sw);
        poff[tt] = lr * 128 + (((tt * 32 + g * 8)) ^ ((lr & 7) << 4));
    }
    #pragma unroll
    for (int c = 0; c < 2; ++c)
        paoff[c] = lr * 128 + ((c * 64 + g * 16) ^ ((lr & 7) << 4));

    const int sgr = lane >> 3;            // staging
    const int sgslot = (lane & 7) * 16;
    const int sgswz = sgr << 4;

    f4 o[4] = {};
    float mrun = -3.0e38f, lrun = 0.f;
    h_t* pw = Pl + wv * 1024;

    for (int kt = 0; kt < SEQ / 64; ++kt) {
        const int kv0 = kt * 64;
        __syncthreads();
        #pragma unroll
        for (int i = 0; i < 2; ++i) {
            const int r = (wv * 2 + i) * 8 + sgr;
            glds16((const char*)K  + ((qkbase + (size_t)(kv0 + r) * DHD) << 1) + (sgslot ^ sgswz),
                   (char*)Kt + (wv * 2 + i) * 1024);
            glds16((const char*)Vt + ((vbase + (size_t)r * SEQ + kv0) << 1) + (sgslot ^ sgswz),
                   (char*)Vs + (wv * 2 + i) * 1024);
        }
        if (t < 64) madd[t] = mask[b * SEQ + kv0 + t] ? -1e9f : 0.f;
        __syncthreads();

        // S^T tiles: [kv 16t][q 16] per wave
        f4 s[4] = {};
        #pragma unroll
        for (int tt = 0; tt < 4; ++tt)
            #pragma unroll
            for (int c = 0; c < 2; ++c) {
                h8 kf = *(const h8*)((const char*)Kt + koff[tt][c]);
                s[tt] = __builtin_amdgcn_mfma_f32_16x16x32_f16(kf, qf[c], s[tt], 0, 0, 0);
            }
        // mask + online softmax (per-lane q = lr)
        float mt_ = -3.0e38f;
        #pragma unroll
        for (int tt = 0; tt < 4; ++tt) {
            f4 ma = *(const f4*)(&madd[tt * 16 + g * 4]);
            s[tt] += ma;
            mt_ = fmaxf(mt_, fmaxf(fmaxf(s[tt][0], s[tt][1]), fmaxf(s[tt][2], s[tt][3])));
        }
        mt_ = fmaxf(mt_, __shfl_xor(mt_, 16, 64));
        mt_ = fmaxf(mt_, __shfl_xor(mt_, 32, 64));

        const bool skip = __all(mt_ <= mrun + 8.f);   // T13 defer-max
        float scl = 1.f;
        if (!skip) {
            const float mnew = fmaxf(mrun, mt_);
            scl = __expf(mrun - mnew);
            mrun = mnew;
        }
        float ps = 0.f;
        #pragma unroll
        for (int tt = 0; tt < 4; ++tt) {
            const float p0 = __expf(s[tt][0] - mrun), p1 = __expf(s[tt][1] - mrun);
            const float p2 = __expf(s[tt][2] - mrun), p3 = __expf(s[tt][3] - mrun);
            ps += p0 + p1 + p2 + p3;
            h4 pq = {(h_t)p0, (h_t)p1, (h_t)p2, (h_t)p3};
            *(h4*)((char*)pw + poff[tt]) = pq;
        }
        ps += __shfl_xor(ps, 16, 64);
        ps += __shfl_xor(ps, 32, 64);
        if (skip) {
            lrun += ps;
        } else {
            lrun = lrun * scl + ps;
            #pragma unroll
            for (int e = 0; e < 4; ++e) {
                const float sce = __shfl(scl, g * 4 + e, 64);
                #pragma unroll
                for (int dt = 0; dt < 4; ++dt) o[dt][e] *= sce;
            }
        }
        // PV: O[q][d] += P[q][kv] @ V[kv][d]
        #pragma unroll
        for (int c = 0; c < 2; ++c) {
            h8 pa = *(const h8*)((const char*)pw + paoff[c]);
            #pragma unroll
            for (int dt = 0; dt < 4; ++dt) {
                h8 vf = *(const h8*)((const char*)Vs + koff[dt][c]);
                o[dt] = __builtin_amdgcn_mfma_f32_16x16x32_f16(pa, vf, o[dt], 0, 0, 0);
            }
        }
    }
    const float gm = gamma[h];
    #pragma unroll
    for (int e = 0; e < 4; ++e) {
        const float inv = gm / __shfl(lrun, g * 4 + e, 64);
        const int row = q0 + wv * 16 + g * 4 + e;
        #pragma unroll
        for (int dt = 0; dt < 4; ++dt)
            out[(size_t)(b * SEQ + row) * DIM + h * DHD + dt * 16 + lr] = (h_t)(o[dt][e] * inv);
    }
}

// ======================= launch =======================
// ws layout (105 MB total; 129 MB proven safe):
//   0 mask(1MB) | 1MB wqkv_t [3072][1024] f16 (6MB) | 7MB wot(2) | 9MB w1t(8) | 17MB w2t(8)
//   25MB  A   : h -> attn_out -> h2
//   41MB  Qb  : Q(head-major) -> proj
//   57MB  Kb  : K(head-major) -> fc1-chunk (32MB spans Kb+Vb)
//   73MB  Vb  : V^T
//   89MB  X2  : x2 fp16 (lives to end)
extern "C" void kernel_launch(void* const* d_in, const int* in_sizes, int n_in,
                              void* d_out, int out_size, void* d_ws, size_t ws_size,
                              hipStream_t stream)
{
    const float* x       = (const float*)d_in[0];
    const void*  kpm     = d_in[1];
    const float* wq      = (const float*)d_in[2];
    const float* wk      = (const float*)d_in[3];
    const float* wv      = (const float*)d_in[4];
    const float* wo      = (const float*)d_in[5];
    const float* gamma   = (const float*)d_in[6];
    const float* ln_g    = (const float*)d_in[7];
    const float* ln_b    = (const float*)d_in[8];
    const float* ln_fc_g = (const float*)d_in[9];
    const float* ln_fc_b = (const float*)d_in[10];
    const float* w1      = (const float*)d_in[11];
    const float* b1      = (const float*)d_in[12];
    const float* w2      = (const float*)d_in[13];
    const float* b2      = (const float*)d_in[14];
    const float* lam     = (const float*)d_in[15];
    float* out = (float*)d_out;

    char* ws = (char*)d_ws;
    const size_t MB = 1 << 20;
    int* mask_i = (int*)ws;
    h_t* wqkvt = (h_t*)(ws + 1  * MB);   // [3072][1024]
    h_t* wqt = wqkvt;
    h_t* wkt = wqkvt + (size_t)1024 * 1024;
    h_t* wvt = wqkvt + (size_t)2048 * 1024;
    h_t* wot = (h_t*)(ws + 7  * MB);
    h_t* w1t = (h_t*)(ws + 9  * MB);
    h_t* w2t = (h_t*)(ws + 17 * MB);
    h_t* bufA = (h_t*)(ws + 25 * MB);
    h_t* bufQ = (h_t*)(ws + 41 * MB);
    h_t* bufK = (h_t*)(ws + 57 * MB);
    h_t* bufV = (h_t*)(ws + 73 * MB);
    h_t* bufX2 = (h_t*)(ws + 89 * MB);

    canon_mask_k<<<NROWS / 256, 256, 0, stream>>>(kpm, mask_i, NROWS);

    wconv4_k<<<dim3(32, 32, 4), 256, 0, stream>>>(wq, wk, wv, wo, wqt, wkt, wvt, wot);
    wconv_k<<<dim3(128, 32), 256, 0, stream>>>(w1, w1t, DIM, FDIM);
    wconv_k<<<dim3(32, 128), 256, 0, stream>>>(w2, w2t, FDIM, DIM);

    // h = LN0(x) -> A (fp16)
    ln1024_k<<<NROWS, 256, 0, stream>>>(x, ln_g, ln_b, bufA);

    // fused QKV: N=3072
    hgemm_k<GEPI_QKV><<<dim3(3072 / 128, NROWS / 128), 256, 0, stream>>>(
        bufA, wqkvt, nullptr, bufQ, NROWS, DIM, 3072, mask_i, nullptr, nullptr, bufK, bufV);

    attn_k<<<dim3(SEQ / 64, NH, NB), 256, 0, stream>>>(bufQ, bufK, bufV, mask_i, gamma, bufA);

    // proj = attn_out @ wo -> Qb (fp16 row-major)
    hgemm_k<GEPI_H16><<<dim3(DIM / 128, NROWS / 128), 256, 0, stream>>>(
        bufA, wot, nullptr, bufQ, NROWS, DIM, DIM, nullptr, nullptr, nullptr, nullptr, nullptr);

    // x2 = LN1(proj)+x -> X2 ; h2 = LN2(x2) -> A   (fused)
    ln_fuse_k<<<NROWS, 256, 0, stream>>>(bufQ, x, ln_g + DIM, ln_b + DIM,
                                         ln_g + 2 * DIM, ln_b + 2 * DIM, bufX2, bufA);

    // FFN, 2 chunks of 4096 rows (fc1 chunk = 32MB in bufK..bufV)
    const int CH = 4096;
    for (int c = 0; c < NROWS / CH; ++c) {
        const size_t ro = (size_t)c * CH;
        hgemm_k<GEPI_GELU><<<dim3(FDIM / 128, CH / 128), 256, 0, stream>>>(
            bufA + ro * DIM, w1t, b1, bufK, CH, DIM, FDIM, nullptr, nullptr, nullptr, nullptr, nullptr);
        ln4096_k<<<CH, 256, 0, stream>>>(bufK, ln_fc_g, ln_fc_b);
        hgemm_k<GEPI_FC2><<<dim3(DIM / 128, CH / 128), 256, 0, stream>>>(
            bufK, w2t, b2, out + ro * DIM, CH, FDIM, DIM, nullptr, bufX2 + ro * DIM, lam, nullptr, nullptr);
    }
}